// Round 1
// baseline (2169.127 us; speedup 1.0000x reference)
//
#include <hip/hip_runtime.h>
#include <math.h>

#define BDIM 4
#define SEQ 2048
#define DMODEL 1024
#define NH 16
#define HD 64
#define MROWS (BDIM*SEQ)          // 8192
#define QKV_ELEMS (BDIM*NH*SEQ*HD) // 8388608 floats = 32 MB

// ---------------------------------------------------------------------------
// GEMM (NT): C[m][e] = sum_k A[m][k] * W[e][k] + bias[e]
// A: [MROWS][1024] row-major, W: [1024][1024] row-major (row = output e)
// MODE 0: scatter output to [B][H][S][HD] head layout (for q/k/v)
// MODE 1: plain [m][e] output (for final projection)
// Tile: 64x64, BK=16, 256 threads, 4x4 micro-tile per thread.
// LDS stored k-major with stride 68 (pad) so micro-tile reads are float4.
// ---------------------------------------------------------------------------
template<int MODE>
__global__ __launch_bounds__(256)
void gemm_nt(const float* __restrict__ A, const float* __restrict__ W,
             const float* __restrict__ bias, float* __restrict__ out) {
  __shared__ float As[16][68];   // [k][m]
  __shared__ float Ws[16][68];   // [k][e]
  const int tid = threadIdx.x;
  const int bm = blockIdx.y * 64;
  const int bn = blockIdx.x * 64;
  const int lr = tid >> 2;          // 0..63 : tile row for loading
  const int lk = (tid & 3) * 4;     // 0,4,8,12 : k offset for loading
  const int tx = tid & 15;          // micro-tile col group
  const int ty = tid >> 4;          // micro-tile row group

  float acc[4][4] = {};
  const float* Arow = A + (size_t)(bm + lr) * DMODEL + lk;
  const float* Wrow = W + (size_t)(bn + lr) * DMODEL + lk;

  for (int kt = 0; kt < DMODEL; kt += 16) {
    float4 a4 = *(const float4*)(Arow + kt);
    float4 w4 = *(const float4*)(Wrow + kt);
    As[lk+0][lr] = a4.x; As[lk+1][lr] = a4.y; As[lk+2][lr] = a4.z; As[lk+3][lr] = a4.w;
    Ws[lk+0][lr] = w4.x; Ws[lk+1][lr] = w4.y; Ws[lk+2][lr] = w4.z; Ws[lk+3][lr] = w4.w;
    __syncthreads();
#pragma unroll
    for (int kk = 0; kk < 16; ++kk) {
      float4 av = *(const float4*)&As[kk][ty*4];
      float4 wv = *(const float4*)&Ws[kk][tx*4];
      float a[4] = {av.x, av.y, av.z, av.w};
      float w[4] = {wv.x, wv.y, wv.z, wv.w};
#pragma unroll
      for (int i = 0; i < 4; ++i)
#pragma unroll
        for (int j = 0; j < 4; ++j) acc[i][j] += a[i] * w[j];
    }
    __syncthreads();
  }

  float4 bv = *(const float4*)&bias[bn + tx*4];
  float bb[4] = {bv.x, bv.y, bv.z, bv.w};

  if (MODE == 0) {
    // whole e-tile lies in one head (bn is 64-aligned, tile width 64)
    const int h = bn >> 6;
    const int m0 = bm + ty*4;
    const int b = m0 >> 11;          // / SEQ
#pragma unroll
    for (int i = 0; i < 4; ++i) {
      const int s = (m0 + i) & (SEQ - 1);
      float4 o = make_float4(acc[i][0]+bb[0], acc[i][1]+bb[1],
                             acc[i][2]+bb[2], acc[i][3]+bb[3]);
      *(float4*)&out[((size_t)(b*NH + h)*SEQ + s)*HD + tx*4] = o;
    }
  } else {
#pragma unroll
    for (int i = 0; i < 4; ++i) {
      const int m = bm + ty*4 + i;
      float4 o = make_float4(acc[i][0]+bb[0], acc[i][1]+bb[1],
                             acc[i][2]+bb[2], acc[i][3]+bb[3]);
      *(float4*)&out[(size_t)m*DMODEL + bn + tx*4] = o;
    }
  }
}

// ---------------------------------------------------------------------------
// RoPE in-place on q and k ([B][H][S][HD]).
// NOTE: reference swaps sin/cos names: c = sin_tab, s = cos_tab, so
//   new1 = x1*sin - x2*cos ; new2 = x2*sin + x1*cos   (still orthogonal)
// ---------------------------------------------------------------------------
__global__ __launch_bounds__(256)
void rope_kernel(float* __restrict__ qbuf, float* __restrict__ kbuf) {
  const int PAIRS = BDIM*NH*SEQ*32;           // 2^22
  int idx = blockIdx.x * 256 + threadIdx.x;    // [0, 2*PAIRS)
  float* base = (idx < PAIRS) ? qbuf : kbuf;
  int r  = idx & (PAIRS - 1);
  int i  = r & 31;
  int s  = (r >> 5) & (SEQ - 1);
  int bh = r >> 16;
  float* p = base + (size_t)bh * SEQ * HD + (size_t)s * HD;
  // inv_freq = 10000^(-i/32); compute in double, round to fp32, then fp32
  // angle multiply — matches numpy's fp32 table to ~1 ulp.
  float freq = (float)pow(10000.0, -(double)i / 32.0);
  float ang  = (float)s * freq;
  float sv = sinf(ang), cv = cosf(ang);
  float x1 = p[i], x2 = p[i + 32];
  p[i]      = x1 * sv - x2 * cv;
  p[i + 32] = x2 * sv + x1 * cv;
}

// ---------------------------------------------------------------------------
// Flash attention, fp32. One block = 64 q-rows of one (b,h).
// LDS: Qt [d][r] (scaled by 1/8), KV buffer reused (K^T [d][j] -> V [j][d]),
// Ss [r][j] scores -> P. All rows padded to stride 68 (bank spread).
// Thread roles:
//   score phase: 16x16 grid, 4x4 micro-tile of S
//   softmax/PV : thread t -> row r=t>>2, d-slice sub=t&3 (16 floats of acc)
// ---------------------------------------------------------------------------
__global__ __launch_bounds__(256)
void flash_attn(const float* __restrict__ q, const float* __restrict__ k,
                const float* __restrict__ v, float* __restrict__ ctx) {
  __shared__ float Qt[64][68];
  __shared__ float KV[64][68];
  __shared__ float Ss[64][68];

  const int tid = threadIdx.x;
  const int bh  = blockIdx.y;
  const int b   = bh >> 4, h = bh & 15;
  const int q0  = blockIdx.x * 64;

  const float* qp = q + ((size_t)bh * SEQ + q0) * HD;
  const float* kp = k + (size_t)bh * SEQ * HD;
  const float* vp = v + (size_t)bh * SEQ * HD;

  const int lrow = tid >> 2;            // 0..63
  const int lc0  = (tid & 3) * 16;      // 0,16,32,48
  const float scale = 0.125f;           // 1/sqrt(64)

  // stage Q tile (transposed, pre-scaled)
#pragma unroll
  for (int ii = 0; ii < 4; ++ii) {
    float4 t = *(const float4*)(qp + (size_t)lrow*HD + lc0 + ii*4);
    int c = lc0 + ii*4;
    Qt[c+0][lrow] = t.x * scale;
    Qt[c+1][lrow] = t.y * scale;
    Qt[c+2][lrow] = t.z * scale;
    Qt[c+3][lrow] = t.w * scale;
  }

  const int r   = tid >> 2;
  const int sub = tid & 3;
  const int tyA = tid >> 4, txA = tid & 15;

  float m_i = -1e30f, l_i = 0.0f;
  float accum[16];
#pragma unroll
  for (int d = 0; d < 16; ++d) accum[d] = 0.0f;

  for (int kt = 0; kt < SEQ; kt += 64) {
    // ---- load K tile into regs
    float4 kreg[4];
#pragma unroll
    for (int ii = 0; ii < 4; ++ii)
      kreg[ii] = *(const float4*)(kp + (size_t)(kt + lrow)*HD + lc0 + ii*4);

    __syncthreads();   // prev iter phase C done (KV, Ss free); iter0: Q staged

#pragma unroll
    for (int ii = 0; ii < 4; ++ii) {
      int c = lc0 + ii*4;
      KV[c+0][lrow] = kreg[ii].x;
      KV[c+1][lrow] = kreg[ii].y;
      KV[c+2][lrow] = kreg[ii].z;
      KV[c+3][lrow] = kreg[ii].w;
    }
    // issue V global loads now so they overlap score compute
    float4 vreg[4];
#pragma unroll
    for (int ii = 0; ii < 4; ++ii)
      vreg[ii] = *(const float4*)(vp + (size_t)(kt + lrow)*HD + lc0 + ii*4);

    __syncthreads();   // K^T visible

    // ---- phase A: scores, 4x4 micro-tile
    float sc[4][4] = {};
#pragma unroll
    for (int d4 = 0; d4 < 16; ++d4) {
      const int d = d4 * 4;
      float4 qv[4], kv[4];
#pragma unroll
      for (int e = 0; e < 4; ++e) qv[e] = *(const float4*)&Qt[d+e][tyA*4];
#pragma unroll
      for (int e = 0; e < 4; ++e) kv[e] = *(const float4*)&KV[d+e][txA*4];
#pragma unroll
      for (int e = 0; e < 4; ++e) {
        float qa[4] = {qv[e].x, qv[e].y, qv[e].z, qv[e].w};
        float kb[4] = {kv[e].x, kv[e].y, kv[e].z, kv[e].w};
#pragma unroll
        for (int i = 0; i < 4; ++i)
#pragma unroll
          for (int j = 0; j < 4; ++j) sc[i][j] += qa[i] * kb[j];
      }
    }
#pragma unroll
    for (int i = 0; i < 4; ++i)
      *(float4*)&Ss[tyA*4 + i][txA*4] =
          make_float4(sc[i][0], sc[i][1], sc[i][2], sc[i][3]);

    __syncthreads();   // scores visible; everyone done reading K^T

    // ---- overwrite KV with V (row-major)
#pragma unroll
    for (int ii = 0; ii < 4; ++ii)
      *(float4*)&KV[lrow][lc0 + ii*4] = vreg[ii];

    // ---- phase B: online softmax on my 16 scores of row r
    float pv[16];
    float lm = -1e30f;
#pragma unroll
    for (int c = 0; c < 4; ++c) {
      float4 t = *(const float4*)&Ss[r][sub*16 + c*4];
      pv[c*4+0] = t.x; pv[c*4+1] = t.y; pv[c*4+2] = t.z; pv[c*4+3] = t.w;
    }
#pragma unroll
    for (int jj = 0; jj < 16; ++jj) lm = fmaxf(lm, pv[jj]);
    lm = fmaxf(lm, __shfl_xor(lm, 1));
    lm = fmaxf(lm, __shfl_xor(lm, 2));
    float mnew = fmaxf(m_i, lm);
    float ls = 0.0f;
#pragma unroll
    for (int jj = 0; jj < 16; ++jj) { pv[jj] = __expf(pv[jj] - mnew); ls += pv[jj]; }
#pragma unroll
    for (int c = 0; c < 4; ++c)
      *(float4*)&Ss[r][sub*16 + c*4] =
          make_float4(pv[c*4+0], pv[c*4+1], pv[c*4+2], pv[c*4+3]);
    ls += __shfl_xor(ls, 1);
    ls += __shfl_xor(ls, 2);
    float alpha = __expf(m_i - mnew);
    l_i = l_i * alpha + ls;
    m_i = mnew;
#pragma unroll
    for (int d = 0; d < 16; ++d) accum[d] *= alpha;

    __syncthreads();   // P and V visible

    // ---- phase C: accum += P[r][:] * V[:, my d-slice]
    for (int j0 = 0; j0 < 64; j0 += 4) {
      float4 p4 = *(const float4*)&Ss[r][j0];
      float pj[4] = {p4.x, p4.y, p4.z, p4.w};
#pragma unroll
      for (int jj = 0; jj < 4; ++jj) {
#pragma unroll
        for (int c = 0; c < 4; ++c) {
          float4 vv = *(const float4*)&KV[j0 + jj][sub*16 + c*4];
          accum[c*4+0] += pj[jj] * vv.x;
          accum[c*4+1] += pj[jj] * vv.y;
          accum[c*4+2] += pj[jj] * vv.z;
          accum[c*4+3] += pj[jj] * vv.w;
        }
      }
    }
  }

  // epilogue: ctx layout [B][S][H*HD]
  float inv = 1.0f / l_i;
  float* op = ctx + ((size_t)(b*SEQ + q0 + r))*DMODEL + h*HD + sub*16;
#pragma unroll
  for (int c = 0; c < 4; ++c) {
    float4 o = make_float4(accum[c*4+0]*inv, accum[c*4+1]*inv,
                           accum[c*4+2]*inv, accum[c*4+3]*inv);
    *(float4*)(op + c*4) = o;
  }
}

// ---------------------------------------------------------------------------
extern "C" void kernel_launch(void* const* d_in, const int* in_sizes, int n_in,
                              void* d_out, int out_size, void* d_ws, size_t ws_size,
                              hipStream_t stream) {
  const float* hs = (const float*)d_in[0];
  const float* Wq = (const float*)d_in[1];
  const float* bq = (const float*)d_in[2];
  const float* Wk = (const float*)d_in[3];
  const float* bk = (const float*)d_in[4];
  const float* Wv = (const float*)d_in[5];
  const float* bv = (const float*)d_in[6];
  const float* Wo = (const float*)d_in[7];
  const float* bo = (const float*)d_in[8];
  float* out = (float*)d_out;

  float* qb = (float*)d_ws;            // 32 MB each, [B][H][S][HD]
  float* kb = qb + QKV_ELEMS;
  float* vb = kb + QKV_ELEMS;
  float* cb = vb + QKV_ELEMS;          // ctx, [B][S][D]

  dim3 gridG(DMODEL/64, MROWS/64);     // (16, 128)
  gemm_nt<0><<<gridG, 256, 0, stream>>>(hs, Wq, bq, qb);
  gemm_nt<0><<<gridG, 256, 0, stream>>>(hs, Wk, bk, kb);
  gemm_nt<0><<<gridG, 256, 0, stream>>>(hs, Wv, bv, vb);

  rope_kernel<<<(2*BDIM*NH*SEQ*32)/256, 256, 0, stream>>>(qb, kb);

  flash_attn<<<dim3(SEQ/64, BDIM*NH), 256, 0, stream>>>(qb, kb, vb, cb);

  gemm_nt<1><<<gridG, 256, 0, stream>>>(cb, Wo, bo, out);
}

// Round 2
// 1038.897 us; speedup vs baseline: 2.0879x; 2.0879x over previous
//
#include <hip/hip_runtime.h>
#include <math.h>

#define SEQ 2048
#define DMODEL 1024
#define NH 16
#define HD 64
#define BH 64                      // B*NH
#define MROWS 8192                 // B*SEQ
#define QKV_U16 8388608            // BH*SEQ*HD elements

typedef __attribute__((ext_vector_type(8))) short short8;
typedef __attribute__((ext_vector_type(4))) float floatx4;

// ---- bf16 helpers (RNE) ----
__device__ inline unsigned short f2bf(float x) {
  union { float f; unsigned u; } v; v.f = x;
  unsigned r = v.u + 0x7FFFu + ((v.u >> 16) & 1u);
  return (unsigned short)(r >> 16);
}
__device__ inline float bf2f(unsigned short h) {
  union { unsigned u; float f; } v; v.u = ((unsigned)h) << 16;
  return v.f;
}

// ---------------------------------------------------------------------------
// Split-bf16 MFMA GEMM (NT): C[m][e] = sum_k A[m][k]*W[e][k] + bias[e]
// A fp32 [M][1024], W fp32 [1024][1024] row-major (row e).
// Split: x = hi + lo (both bf16); C ~= Ah.Wh + Al.Wh + Ah.Wl  (fp32-grade).
// Tile 128m x 64n, BK=32, 256 threads (4 waves), wave owns 32m x 64n.
// MODE 0: bf16 output scattered to [BH][SEQ][64]  (q/k/v)
// MODE 1: fp32 output [m][1024]                    (final proj)
// ---------------------------------------------------------------------------
template<int MODE>
__global__ __launch_bounds__(256, 2)
void gemm_split(const float* __restrict__ A, const float* __restrict__ W,
                const float* __restrict__ bias, void* __restrict__ outp) {
  __shared__ float As[128][36];
  __shared__ float Ws[64][36];
  const int tid  = threadIdx.x;
  const int wave = tid >> 6;
  const int lane = tid & 63;
  const int fr   = lane & 15;        // frag row (m or n within 16-tile)
  const int fg   = lane >> 4;        // quad
  const int fk   = fg * 8;           // k offset within 32
  const int bm   = blockIdx.y * 128;
  const int bn   = blockIdx.x * 64;

  floatx4 acc[2][4];
#pragma unroll
  for (int i = 0; i < 2; ++i)
#pragma unroll
    for (int j = 0; j < 4; ++j) acc[i][j] = (floatx4){0.f, 0.f, 0.f, 0.f};

  for (int kt = 0; kt < DMODEL; kt += 32) {
    // stage A 128x32, W 64x32 (fp32, coalesced: 8 lanes per row)
#pragma unroll
    for (int i = 0; i < 4; ++i) {
      int f = tid + i * 256; int r = f >> 3, c = (f & 7) * 4;
      *(float4*)&As[r][c] = *(const float4*)(A + (size_t)(bm + r) * DMODEL + kt + c);
    }
#pragma unroll
    for (int i = 0; i < 2; ++i) {
      int f = tid + i * 256; int r = f >> 3, c = (f & 7) * 4;
      *(float4*)&Ws[r][c] = *(const float4*)(W + (size_t)(bn + r) * DMODEL + kt + c);
    }
    __syncthreads();

    short8 afh[2], afl[2], bfh[4], bfl[4];
#pragma unroll
    for (int tm = 0; tm < 2; ++tm) {
      const float* p = &As[wave * 32 + tm * 16 + fr][fk];
      float4 x0 = *(const float4*)p, x1 = *(const float4*)(p + 4);
      float xs[8] = {x0.x, x0.y, x0.z, x0.w, x1.x, x1.y, x1.z, x1.w};
#pragma unroll
      for (int j = 0; j < 8; ++j) {
        unsigned short h = f2bf(xs[j]);
        afh[tm][j] = (short)h;
        afl[tm][j] = (short)f2bf(xs[j] - bf2f(h));
      }
    }
#pragma unroll
    for (int tn = 0; tn < 4; ++tn) {
      const float* p = &Ws[tn * 16 + fr][fk];
      float4 x0 = *(const float4*)p, x1 = *(const float4*)(p + 4);
      float xs[8] = {x0.x, x0.y, x0.z, x0.w, x1.x, x1.y, x1.z, x1.w};
#pragma unroll
      for (int j = 0; j < 8; ++j) {
        unsigned short h = f2bf(xs[j]);
        bfh[tn][j] = (short)h;
        bfl[tn][j] = (short)f2bf(xs[j] - bf2f(h));
      }
    }

#pragma unroll
    for (int tm = 0; tm < 2; ++tm)
#pragma unroll
      for (int tn = 0; tn < 4; ++tn) {
        acc[tm][tn] = __builtin_amdgcn_mfma_f32_16x16x32_bf16(afh[tm], bfh[tn], acc[tm][tn], 0, 0, 0);
        acc[tm][tn] = __builtin_amdgcn_mfma_f32_16x16x32_bf16(afl[tm], bfh[tn], acc[tm][tn], 0, 0, 0);
        acc[tm][tn] = __builtin_amdgcn_mfma_f32_16x16x32_bf16(afh[tm], bfl[tn], acc[tm][tn], 0, 0, 0);
      }
    __syncthreads();
  }

  // epilogue
  float bias_s[4];
#pragma unroll
  for (int tn = 0; tn < 4; ++tn) bias_s[tn] = bias[bn + tn * 16 + fr];

#pragma unroll
  for (int tm = 0; tm < 2; ++tm)
#pragma unroll
    for (int tn = 0; tn < 4; ++tn)
#pragma unroll
      for (int r = 0; r < 4; ++r) {
        float val = acc[tm][tn][r] + bias_s[tn];
        int m = bm + wave * 32 + tm * 16 + fg * 4 + r;
        if (MODE == 0) {
          int h = bn >> 6;                 // 64-wide n-tile = one head
          int d = tn * 16 + fr;
          int b = m >> 11, s = m & (SEQ - 1);
          ((unsigned short*)outp)[((size_t)(b * NH + h) * SEQ + s) * HD + d] = f2bf(val);
        } else {
          ((float*)outp)[(size_t)m * DMODEL + bn + tn * 16 + fr] = val;
        }
      }
}

// ---------------------------------------------------------------------------
// freq table: inv_freq[i] = 10000^(-i/32), i<32 (double pow, once, tiny)
// ---------------------------------------------------------------------------
__global__ void freq_kernel(float* f) {
  int i = threadIdx.x;
  if (i < 32) f[i] = (float)pow(10000.0, -(double)i / 32.0);
}

// ---------------------------------------------------------------------------
// RoPE on bf16 q/k in place. Reference swaps sin/cos names:
//   new1 = x1*sin - x2*cos ; new2 = x2*sin + x1*cos
// Thread handles 4 (i, i+32) pairs of one row.
// ---------------------------------------------------------------------------
__global__ __launch_bounds__(256)
void rope_bf16(unsigned short* __restrict__ qb, unsigned short* __restrict__ kb,
               const float* __restrict__ freq) {
  const int HALF = BH * SEQ * 8;                   // 1,048,576
  int idx = blockIdx.x * 256 + threadIdx.x;
  unsigned short* base = (idx < HALF) ? qb : kb;
  int r = idx & (HALF - 1);
  int quad = r & 7;
  int s = (r >> 3) & (SEQ - 1);
  int bh = r >> 14;
  unsigned short* p = base + ((size_t)bh * SEQ + s) * HD + quad * 4;

  uint2 ra = *(const uint2*)p;
  uint2 rb = *(const uint2*)(p + 32);
  unsigned short a16[4] = {(unsigned short)(ra.x & 0xFFFF), (unsigned short)(ra.x >> 16),
                           (unsigned short)(ra.y & 0xFFFF), (unsigned short)(ra.y >> 16)};
  unsigned short b16[4] = {(unsigned short)(rb.x & 0xFFFF), (unsigned short)(rb.x >> 16),
                           (unsigned short)(rb.y & 0xFFFF), (unsigned short)(rb.y >> 16)};
  unsigned short o1[4], o2[4];
#pragma unroll
  for (int e = 0; e < 4; ++e) {
    int i = quad * 4 + e;
    float ang = (float)s * freq[i];
    float sv = sinf(ang), cv = cosf(ang);
    float x1 = bf2f(a16[e]), x2 = bf2f(b16[e]);
    o1[e] = f2bf(x1 * sv - x2 * cv);
    o2[e] = f2bf(x2 * sv + x1 * cv);
  }
  uint2 wa = {(unsigned)o1[0] | ((unsigned)o1[1] << 16), (unsigned)o1[2] | ((unsigned)o1[3] << 16)};
  uint2 wb = {(unsigned)o2[0] | ((unsigned)o2[1] << 16), (unsigned)o2[2] | ((unsigned)o2[3] << 16)};
  *(uint2*)p = wa;
  *(uint2*)(p + 32) = wb;
}

// ---------------------------------------------------------------------------
// Transpose V: [BH][SEQ][64] bf16 -> Vt [BH][64][SEQ] bf16. 64x64 LDS tiles.
// ---------------------------------------------------------------------------
__global__ __launch_bounds__(256)
void transpose_v(const unsigned short* __restrict__ v, unsigned short* __restrict__ vt) {
  __shared__ unsigned short T[64][72];
  const int t = threadIdx.x;
  const int bh = blockIdx.y;
  const int s0 = blockIdx.x * 64;
  const unsigned short* vp = v + ((size_t)bh * SEQ + s0) * HD;
#pragma unroll
  for (int h = 0; h < 2; ++h) {
    int row = t >> 2, c = (t & 3) * 16 + h * 8;
    *(short8*)&T[row][c] = *(const short8*)(vp + (size_t)row * HD + c);
  }
  __syncthreads();
  int d = t >> 2, sc = (t & 3) * 16;
  unsigned short tmp[16];
#pragma unroll
  for (int e = 0; e < 16; ++e) tmp[e] = T[sc + e][d];
  unsigned short* op = vt + ((size_t)bh * HD + d) * SEQ + s0 + sc;
#pragma unroll
  for (int h = 0; h < 2; ++h) {
    short8 w;
#pragma unroll
    for (int e = 0; e < 8; ++e) w[e] = (short)tmp[h * 8 + e];
    *(short8*)(op + h * 8) = w;
  }
}

// ---------------------------------------------------------------------------
// Flash attention, bf16 MFMA. Grid (SEQ/64, BH), 256 thr = 4 waves.
// Wave owns 16 q-rows; kv-tile = 64 keys.
// Scores: S[16q][64k] = Q(A-frag) x K(B-frag, NT) -> C-layout
//   (col=lane&15 -> key j, row=(lane>>4)*4+reg -> query i).
// Softmax stats per reg-row, reduced over 16-lane groups via shfl_xor.
// P -> per-wave LDS (bf16) -> A-frag; V^T B-frags direct from global.
// No __syncthreads anywhere (all LDS is wave-private, DS is in-order).
// ---------------------------------------------------------------------------
__global__ __launch_bounds__(256)
void flash_mfma(const unsigned short* __restrict__ q, const unsigned short* __restrict__ k,
                const unsigned short* __restrict__ vt, float* __restrict__ ctx) {
  __shared__ unsigned short Pbuf[4][16][72];
  const int tid = threadIdx.x;
  const int wave = tid >> 6;
  const int lane = tid & 63;
  const int fr = lane & 15;
  const int fg = lane >> 4;
  const int fk = fg * 8;
  const int bh = blockIdx.y;
  const int q0 = blockIdx.x * 64 + wave * 16;

  const unsigned short* qp = q + ((size_t)bh * SEQ + q0) * HD;
  const unsigned short* kp = k + (size_t)bh * SEQ * HD;
  const unsigned short* vp = vt + (size_t)bh * HD * SEQ;

  // Q A-frags (held all kernel): row = fr, k-window ks*32+fk
  short8 qf[2];
#pragma unroll
  for (int ks = 0; ks < 2; ++ks)
    qf[ks] = *(const short8*)(qp + (size_t)fr * HD + ks * 32 + fk);

  floatx4 oacc[4];
#pragma unroll
  for (int i = 0; i < 4; ++i) oacc[i] = (floatx4){0.f, 0.f, 0.f, 0.f};
  float mrow[4] = {-1e30f, -1e30f, -1e30f, -1e30f};
  float lrow[4] = {0.f, 0.f, 0.f, 0.f};

  for (int kt = 0; kt < SEQ; kt += 64) {
    // ---- scores
    floatx4 s4[4];
#pragma unroll
    for (int jt = 0; jt < 4; ++jt) s4[jt] = (floatx4){0.f, 0.f, 0.f, 0.f};
#pragma unroll
    for (int jt = 0; jt < 4; ++jt)
#pragma unroll
      for (int ks = 0; ks < 2; ++ks) {
        short8 kf = *(const short8*)(kp + (size_t)(kt + jt * 16 + fr) * HD + ks * 32 + fk);
        s4[jt] = __builtin_amdgcn_mfma_f32_16x16x32_bf16(qf[ks], kf, s4[jt], 0, 0, 0);
      }

    // ---- online softmax (scale 1/8)
    float sv[4][4];
#pragma unroll
    for (int jt = 0; jt < 4; ++jt)
#pragma unroll
      for (int r = 0; r < 4; ++r) sv[jt][r] = s4[jt][r] * 0.125f;

    float rmax[4];
#pragma unroll
    for (int r = 0; r < 4; ++r)
      rmax[r] = fmaxf(fmaxf(sv[0][r], sv[1][r]), fmaxf(sv[2][r], sv[3][r]));
#pragma unroll
    for (int d = 1; d <= 8; d <<= 1)
#pragma unroll
      for (int r = 0; r < 4; ++r) rmax[r] = fmaxf(rmax[r], __shfl_xor(rmax[r], d));

    float alpha[4], rsum[4] = {0.f, 0.f, 0.f, 0.f};
#pragma unroll
    for (int r = 0; r < 4; ++r) {
      float mnew = fmaxf(mrow[r], rmax[r]);
      alpha[r] = __expf(mrow[r] - mnew);
      mrow[r] = mnew;
    }
    unsigned short pb[4][4];
#pragma unroll
    for (int jt = 0; jt < 4; ++jt)
#pragma unroll
      for (int r = 0; r < 4; ++r) {
        float p = __expf(sv[jt][r] - mrow[r]);
        unsigned short pu = f2bf(p);
        pb[jt][r] = pu;
        rsum[r] += bf2f(pu);             // sum the rounded value (consistency)
      }
#pragma unroll
    for (int d = 1; d <= 8; d <<= 1)
#pragma unroll
      for (int r = 0; r < 4; ++r) rsum[r] += __shfl_xor(rsum[r], d);
#pragma unroll
    for (int r = 0; r < 4; ++r) lrow[r] = lrow[r] * alpha[r] + rsum[r];

    // rescale O
#pragma unroll
    for (int dt = 0; dt < 4; ++dt)
#pragma unroll
      for (int r = 0; r < 4; ++r) oacc[dt][r] *= alpha[r];

    // ---- P to wave-private LDS (C-layout -> row-major)
#pragma unroll
    for (int jt = 0; jt < 4; ++jt)
#pragma unroll
      for (int r = 0; r < 4; ++r)
        Pbuf[wave][fg * 4 + r][jt * 16 + fr] = pb[jt][r];

    // ---- PV: ctx[16q][64d] += P[16][64] x V[64][64]
#pragma unroll
    for (int js = 0; js < 2; ++js) {
      short8 pf8 = *(const short8*)&Pbuf[wave][fr][js * 32 + fk];
#pragma unroll
      for (int dt = 0; dt < 4; ++dt) {
        short8 vf = *(const short8*)(vp + (size_t)(dt * 16 + fr) * SEQ + kt + js * 32 + fk);
        oacc[dt] = __builtin_amdgcn_mfma_f32_16x16x32_bf16(pf8, vf, oacc[dt], 0, 0, 0);
      }
    }
  }

  // ---- epilogue: ctx [B][S][1024] fp32
  const int b = bh >> 4, h = bh & 15;
  float inv[4];
#pragma unroll
  for (int r = 0; r < 4; ++r) inv[r] = 1.0f / lrow[r];
#pragma unroll
  for (int dt = 0; dt < 4; ++dt)
#pragma unroll
    for (int r = 0; r < 4; ++r)
      ctx[((size_t)(b * SEQ + q0 + fg * 4 + r)) * DMODEL + h * HD + dt * 16 + fr] =
          oacc[dt][r] * inv[r];
}

// ---------------------------------------------------------------------------
extern "C" void kernel_launch(void* const* d_in, const int* in_sizes, int n_in,
                              void* d_out, int out_size, void* d_ws, size_t ws_size,
                              hipStream_t stream) {
  const float* hs = (const float*)d_in[0];
  const float* Wq = (const float*)d_in[1];
  const float* bq = (const float*)d_in[2];
  const float* Wk = (const float*)d_in[3];
  const float* bk = (const float*)d_in[4];
  const float* Wv = (const float*)d_in[5];
  const float* bv = (const float*)d_in[6];
  const float* Wo = (const float*)d_in[7];
  const float* bo = (const float*)d_in[8];

  unsigned short* qb  = (unsigned short*)d_ws;       // bf16 [BH][S][64], 16 MB
  unsigned short* kb  = qb + QKV_U16;
  unsigned short* vb  = kb + QKV_U16;
  unsigned short* vtb = vb + QKV_U16;                // bf16 [BH][64][S]
  float* cb   = (float*)(vtb + QKV_U16);             // fp32 ctx [B][S][D], 32 MB
  float* freq = cb + (size_t)MROWS * DMODEL;         // 32 floats

  freq_kernel<<<1, 32, 0, stream>>>(freq);

  dim3 gridG(DMODEL / 64, MROWS / 128);              // (16, 64)
  gemm_split<0><<<gridG, 256, 0, stream>>>(hs, Wq, bq, qb);
  gemm_split<0><<<gridG, 256, 0, stream>>>(hs, Wk, bk, kb);
  gemm_split<0><<<gridG, 256, 0, stream>>>(hs, Wv, bv, vb);

  rope_bf16<<<(2 * BH * SEQ * 8) / 256, 256, 0, stream>>>(qb, kb, freq);
  transpose_v<<<dim3(SEQ / 64, BH), 256, 0, stream>>>(vb, vtb);

  flash_mfma<<<dim3(SEQ / 64, BH), 256, 0, stream>>>(qb, kb, vtb, cb);

  gemm_split<1><<<gridG, 256, 0, stream>>>(cb, Wo, bo, d_out);
}